// Round 4
// baseline (209.904 us; speedup 1.0000x reference)
//
#include <hip/hip_runtime.h>
#include <hip/hip_bf16.h>
#include <stdint.h>

#define NN 4096
#define NF 128
#define NSPLIT 16
#define XROWS 4

using f32x4  = __attribute__((ext_vector_type(4))) float;
using bf16x8 = __attribute__((ext_vector_type(8))) __bf16;
using u16x8  = __attribute__((ext_vector_type(8))) uint16_t;

__device__ __forceinline__ uint16_t f2b(float f) {
    union { float f; uint32_t u; } v; v.f = f;
    uint32_t r = v.u + 0x7FFFu + ((v.u >> 16) & 1u);
    return (uint16_t)(r >> 16);
}

__device__ __forceinline__ float b2f(uint16_t u) {
    union { uint32_t u; float f; } v; v.u = ((uint32_t)u) << 16;
    return v.f;
}

// ---------------------------------------------------------------------------
// Kernel 1: XW = X@W (4 rows/block), s_col/s_row scores, XWT bf16 (ushort4 store)
// ---------------------------------------------------------------------------
__global__ __launch_bounds__(128) void xw_kernel(
    const float* __restrict__ X, const float* __restrict__ W,
    const float* __restrict__ a,
    uint16_t* __restrict__ XWT,
    float* __restrict__ s_col, float* __restrict__ s_row) {
    __shared__ float xs[XROWS][NF];
    __shared__ float red[XROWS][2][2];
    const int i0 = blockIdx.x * XROWS, f = threadIdx.x;
    #pragma unroll
    for (int r = 0; r < XROWS; ++r) xs[r][f] = X[(size_t)(i0 + r) * NF + f];
    __syncthreads();
    float acc[XROWS] = {0.f, 0.f, 0.f, 0.f};
    #pragma unroll 4
    for (int k = 0; k < NF; ++k) {
        const float w = W[k * NF + f];
        #pragma unroll
        for (int r = 0; r < XROWS; ++r) acc[r] += xs[r][k] * w;
    }
    ushort4 xo;
    xo.x = f2b(acc[0]); xo.y = f2b(acc[1]); xo.z = f2b(acc[2]); xo.w = f2b(acc[3]);
    *(ushort4*)(XWT + (size_t)f * NN + i0) = xo;
    const float a1 = a[f], a2 = a[NF + f];
    #pragma unroll
    for (int r = 0; r < XROWS; ++r) {
        float sc = acc[r] * a1;
        float sr = acc[r] * a2;
        #pragma unroll
        for (int off = 32; off; off >>= 1) {
            sc += __shfl_down(sc, off);
            sr += __shfl_down(sr, off);
        }
        if ((f & 63) == 0) { red[r][f >> 6][0] = sc; red[r][f >> 6][1] = sr; }
    }
    __syncthreads();
    if (f < XROWS) {
        s_col[i0 + f] = red[f][0][0] + red[f][1][0];
        s_row[i0 + f] = red[f][0][1] + red[f][1][1];
    }
}

// ---------------------------------------------------------------------------
// Kernel 2: prep — brute-force order statistics (O(N^2) counting, fully parallel)
//   blocks 0..127  : rank of each k by (s_row[k], k); scatter ks/w1s/w2s
//   blocks 128..255: rec[j] = {C[j] bitcast, exp(s_col), exp(.01 s_col), s_col}
//                    with C[j] = #{k : s_row[k] <= -s_col[j]}
// ---------------------------------------------------------------------------
__global__ __launch_bounds__(256) void prep_kernel(
    const float* __restrict__ s_row, const float* __restrict__ s_col,
    int* __restrict__ ks, float* __restrict__ w1s, float* __restrict__ w2s,
    float4* __restrict__ rec) {
    __shared__ __align__(16) float sr[NN];
    const int t = threadIdx.x;
    #pragma unroll
    for (int c = 0; c < 16; ++c) sr[t + c * 256] = s_row[t + c * 256];
    __syncthreads();
    const bool isC = blockIdx.x >= 128;
    const int tgt = (blockIdx.x & 127) * 32 + (t >> 3);
    const int sub = t & 7;
    const float4* sr4 = (const float4*)sr;
    int cnt = 0;
    if (!isC) {
        const float s = sr[tgt];
        #pragma unroll 4
        for (int q = 0; q < 128; ++q) {
            const int k4 = q * 8 + sub;          // distinct bank quad per sub
            float4 v = sr4[k4];
            const int kb = k4 * 4;
            cnt += (v.x < s) | ((v.x == s) & (kb + 0 < tgt));
            cnt += (v.y < s) | ((v.y == s) & (kb + 1 < tgt));
            cnt += (v.z < s) | ((v.z == s) & (kb + 2 < tgt));
            cnt += (v.w < s) | ((v.w == s) & (kb + 3 < tgt));
        }
    } else {
        const float th = -s_col[tgt];
        #pragma unroll 4
        for (int q = 0; q < 128; ++q) {
            float4 v = sr4[q * 8 + sub];
            cnt += (v.x <= th) + (v.y <= th) + (v.z <= th) + (v.w <= th);
        }
    }
    cnt += __shfl_down(cnt, 4);
    cnt += __shfl_down(cnt, 2);
    cnt += __shfl_down(cnt, 1);
    if (sub == 0) {
        if (!isC) {
            const float s = sr[tgt];
            ks[cnt]  = tgt;
            w1s[cnt] = __expf(s);
            w2s[cnt] = __expf(0.01f * s);
        } else {
            const float sc = s_col[tgt];
            rec[tgt] = (float4){__int_as_float(cnt), __expf(sc), __expf(0.01f * sc), sc};
        }
    }
}

// ---------------------------------------------------------------------------
// Kernel 3: per-row exact num/att via dual scan (replaces A@den GEMM).
//   num[i,j] = ec1[j]*SUF1[C[j]] + ec2[j]*PRE2[C[j]]
//   att[i,j] = den(i,j)/num[i,j],  den = exp(lrelu(s_row[i]+s_col[j]))
// Side effect: bf16 copy of A row.
// ---------------------------------------------------------------------------
#define PB(b) ((b) + (((b) >> 4) << 1))   // +4B pad per 16 elements, keeps pairs adjacent & aligned

__global__ __launch_bounds__(512, 8) void row_kernel(
    const float* __restrict__ A,
    const float* __restrict__ s_row,
    const int* __restrict__ ks, const float* __restrict__ w1s, const float* __restrict__ w2s,
    const float4* __restrict__ rec,
    uint16_t* __restrict__ Ab, uint16_t* __restrict__ att) {
    __shared__ __align__(16) float rowA[NN];                 // 16384 B
    __shared__ __align__(16) uint16_t S1[4640];              // 9280 B  (SUF1, bf16, padded)
    __shared__ __align__(16) uint16_t S2[4640];              // 9280 B  (PRE2, bf16, padded)
    __shared__ float wtot[2][8];
    const int i = blockIdx.x, t = threadIdx.x;

    // 1. stage A row (fp32) + emit bf16 copy
    {
        const float4* Ar = (const float4*)(A + (size_t)i * NN);
        ushort4* Abr = (ushort4*)(Ab + (size_t)i * NN);
        #pragma unroll
        for (int c = 0; c < 2; ++c) {
            float4 v = Ar[t + c * 512];
            ((float4*)rowA)[t + c * 512] = v;
            ushort4 o; o.x = f2b(v.x); o.y = f2b(v.y); o.z = f2b(v.z); o.w = f2b(v.w);
            Abr[t + c * 512] = o;
        }
    }
    __syncthreads();

    // 2. gather own 8 sorted elements straight into registers, dual local prefix
    float l1[8], l2[8];
    {
        const int4*   k4 = (const int4*)ks;
        const float4* a4 = (const float4*)w1s;
        const float4* b4 = (const float4*)w2s;
        float run1 = 0.f, run2 = 0.f;
        #pragma unroll
        for (int g = 0; g < 2; ++g) {
            int4   kk = k4[2 * t + g];
            float4 wa = a4[2 * t + g];
            float4 wb = b4[2 * t + g];
            float g0 = rowA[kk.x], g1 = rowA[kk.y], g2 = rowA[kk.z], g3 = rowA[kk.w];
            run1 += g0 * wa.x; l1[4 * g + 0] = run1;  run2 += g0 * wb.x; l2[4 * g + 0] = run2;
            run1 += g1 * wa.y; l1[4 * g + 1] = run1;  run2 += g1 * wb.y; l2[4 * g + 1] = run2;
            run1 += g2 * wa.z; l1[4 * g + 2] = run1;  run2 += g2 * wb.z; l2[4 * g + 2] = run2;
            run1 += g3 * wa.w; l1[4 * g + 3] = run1;  run2 += g3 * wb.w; l2[4 * g + 3] = run2;
        }
    }
    float s1 = l1[7], s2 = l2[7];
    const int lane = t & 63, wid = t >> 6;
    #pragma unroll
    for (int off = 1; off < 64; off <<= 1) {
        float u1 = __shfl_up(s1, off);
        float u2 = __shfl_up(s2, off);
        if (lane >= off) { s1 += u1; s2 += u2; }
    }
    if (lane == 63) { wtot[0][wid] = s1; wtot[1][wid] = s2; }
    __syncthreads();

    // 3. cross-wave offsets + totals; write SUF1/PRE2 as packed bf16 pairs
    float off1 = 0.f, off2 = 0.f, tot1 = 0.f, tot2 = 0.f;
    #pragma unroll
    for (int w = 0; w < 8; ++w) {
        const float va = wtot[0][w], vb = wtot[1][w];
        tot1 += va; tot2 += vb;
        if (w < wid) { off1 += va; off2 += vb; }
    }
    const float ex1 = off1 + s1 - l1[7];   // exclusive prefix (threads before me), array 1
    const float ex2 = off2 + s2 - l2[7];
    {
        uint32_t* q1 = (uint32_t*)S1;
        uint32_t* q2 = (uint32_t*)S2;
        const int qb = t * 4 + (t >> 1);   // PB(8t)/2
        #pragma unroll
        for (int m = 0; m < 4; ++m) {
            const float pl1 = m ? l1[2 * m - 1] : 0.f;   // l1[e-1] for e=2m
            const float pl2 = m ? l2[2 * m - 1] : 0.f;
            const float sa = tot1 - ex1 - pl1;           // SUF1[8t+2m]
            const float sb = tot1 - ex1 - l1[2 * m];     // SUF1[8t+2m+1]
            const float pa = ex2 + pl2;                  // PRE2[8t+2m]
            const float pb = ex2 + l2[2 * m];            // PRE2[8t+2m+1]
            q1[qb + m] = (uint32_t)f2b(sa) | ((uint32_t)f2b(sb) << 16);
            q2[qb + m] = (uint32_t)f2b(pa) | ((uint32_t)f2b(pb) << 16);
        }
    }
    if (t == 511) {                        // tail entry C = 4096
        S1[PB(4096)] = 0;                  // empty suffix
        S2[PB(4096)] = f2b(tot2);          // full prefix
    }
    __syncthreads();

    // 4. per-j att: fully-coalesced rec loads, packed-bf16 u32 stores
    const float sri = s_row[i];
    uint32_t* attR = (uint32_t*)(att + (size_t)i * NN);
    #pragma unroll
    for (int e = 0; e < 4; ++e) {
        const int j0 = e * 1024 + 2 * t;
        const float4 ra = rec[j0];
        const float4 rb = rec[j0 + 1];
        const int Ca = __float_as_int(ra.x);
        const int Cb = __float_as_int(rb.x);
        const float numa = ra.y * b2f(S1[PB(Ca)]) + ra.z * b2f(S2[PB(Ca)]);
        const float numb = rb.y * b2f(S1[PB(Cb)]) + rb.z * b2f(S2[PB(Cb)]);
        float za = sri + ra.w; za = za > 0.f ? za : 0.01f * za;
        float zb = sri + rb.w; zb = zb > 0.f ? zb : 0.01f * zb;
        const float dena = __expf(za);
        const float denb = __expf(zb);
        const float va = (numa != 0.f) ? dena * __builtin_amdgcn_rcpf(numa) : 0.f;
        const float vb = (numb != 0.f) ? denb * __builtin_amdgcn_rcpf(numb) : 0.f;
        attR[e * 512 + t] = (uint32_t)f2b(va) | ((uint32_t)f2b(vb) << 16);
    }
}

// ---------------------------------------------------------------------------
// Kernel 4: skinny GEMM split-K, NO LDS — direct global->register MFMA frags.
// B (128 x 4096 bf16, 1 MB) is L2-resident; A streamed once.
// P stored column-major per split: P[split][j][i]
// ---------------------------------------------------------------------------
__global__ __launch_bounds__(256) void gemm_splitk_kernel(
    const uint16_t* __restrict__ Abt, const uint16_t* __restrict__ Bt,
    float* __restrict__ P) {
    const int bm0 = blockIdx.y * 128;
    const int split = blockIdx.z;
    const int kBeg = split * (NN / NSPLIT);
    const int lane = threadIdx.x & 63, wid = threadIdx.x >> 6;
    const int wy = wid >> 1, wx = wid & 1;
    const int quad = lane >> 4, l16 = lane & 15;

    f32x4 acc[4][4];
    #pragma unroll
    for (int mi = 0; mi < 4; ++mi)
        #pragma unroll
        for (int ni = 0; ni < 4; ++ni)
            acc[mi][ni] = (f32x4){0.f, 0.f, 0.f, 0.f};

    const uint16_t* Ap = Abt + (size_t)(bm0 + wy * 64 + l16) * NN + quad * 8;
    const uint16_t* Bp = Bt  + (size_t)(wx * 64 + l16) * NN + quad * 8;

    #pragma unroll 2
    for (int kk = 0; kk < NN / NSPLIT; kk += 32) {
        const int k0 = kBeg + kk;
        bf16x8 af[4], bf[4];
        #pragma unroll
        for (int mi = 0; mi < 4; ++mi)
            af[mi] = *(const bf16x8*)(Ap + (size_t)(mi * 16) * NN + k0);
        #pragma unroll
        for (int ni = 0; ni < 4; ++ni)
            bf[ni] = *(const bf16x8*)(Bp + (size_t)(ni * 16) * NN + k0);
        #pragma unroll
        for (int mi = 0; mi < 4; ++mi)
            #pragma unroll
            for (int ni = 0; ni < 4; ++ni)
                acc[mi][ni] = __builtin_amdgcn_mfma_f32_16x16x32_bf16(af[mi], bf[ni], acc[mi][ni], 0, 0, 0);
    }

    float* Pp = P + (size_t)split * (NN * NF);
    #pragma unroll
    for (int mi = 0; mi < 4; ++mi) {
        const int i0 = bm0 + wy * 64 + mi * 16 + quad * 4;
        #pragma unroll
        for (int ni = 0; ni < 4; ++ni) {
            const int j = wx * 64 + ni * 16 + l16;
            *(f32x4*)(Pp + (size_t)j * NN + i0) = acc[mi][ni];
        }
    }
}

// ---------------------------------------------------------------------------
// Reduce kernels (P is [split][j][i] col-major)
// ---------------------------------------------------------------------------
__global__ __launch_bounds__(256) void reduce_t_kernel(
    const float* __restrict__ P, uint16_t* __restrict__ M1T) {
    const int idx = (blockIdx.x * 256 + threadIdx.x) * 4;
    f32x4 s = (f32x4){0.f, 0.f, 0.f, 0.f};
    #pragma unroll
    for (int sp = 0; sp < NSPLIT; ++sp)
        s += *(const f32x4*)(P + (size_t)sp * (NN * NF) + idx);
    ushort4 o;
    o.x = f2b(s[0]); o.y = f2b(s[1]); o.z = f2b(s[2]); o.w = f2b(s[3]);
    *(ushort4*)(M1T + idx) = o;
}

// block: 16 i-rows x all 128 j; coalesced P reads, LDS transpose, contiguous H writes
__global__ __launch_bounds__(256) void reduce_out_kernel(
    const float* __restrict__ P, float* __restrict__ out) {
    __shared__ float acc[NF][17];
    const int i0 = blockIdx.x * 16;
    const int t = threadIdx.x;
    const int ii = t & 15, jb = t >> 4;          // load role: 16 j-groups x 16 i
    float local[8];
    #pragma unroll
    for (int jj = 0; jj < 8; ++jj) local[jj] = 0.f;
    for (int sp = 0; sp < NSPLIT; ++sp) {
        const float* Pp = P + (size_t)sp * (NN * NF) + i0 + ii;
        #pragma unroll
        for (int jj = 0; jj < 8; ++jj)
            local[jj] += Pp[(size_t)(jb + jj * 16) * NN];
    }
    #pragma unroll
    for (int jj = 0; jj < 8; ++jj) acc[jb + jj * 16][ii] = local[jj];
    __syncthreads();
    const int j = t & 127, rb = t >> 7;          // write role: rows of H
    #pragma unroll
    for (int p = 0; p < 8; ++p) {
        const int r = rb + p * 2;
        out[(size_t)(i0 + r) * NF + j] = acc[j][r];
    }
}

// ---------------------------------------------------------------------------
extern "C" void kernel_launch(void* const* d_in, const int* in_sizes, int n_in,
                              void* d_out, int out_size, void* d_ws, size_t ws_size,
                              hipStream_t stream) {
    (void)in_sizes; (void)n_in; (void)out_size; (void)ws_size;
    const float* X = (const float*)d_in[0];
    const float* A = (const float*)d_in[1];
    const float* W = (const float*)d_in[2];
    const float* a = (const float*)d_in[3];
    float* H = (float*)d_out;

    char* ws = (char*)d_ws;
    uint16_t* Ab  = (uint16_t*)(ws);                       // 32 MB bf16 A
    uint16_t* att = (uint16_t*)(ws + ((size_t)32 << 20));  // 32 MB bf16 att
    float*    P   = (float*)   (ws + ((size_t)64 << 20));  // 32 MB split-K partials
    uint16_t* XWT = (uint16_t*)(ws + ((size_t)96 << 20));  // 1 MB
    uint16_t* M1T = (uint16_t*)(ws + ((size_t)97 << 20));  // 1 MB
    // small arrays live inside P's region (dead before first P write)
    char* sm = ws + ((size_t)64 << 20);
    float*  s_col = (float*) (sm);
    float*  s_row = (float*) (sm + (16 << 10));
    int*    ks    = (int*)   (sm + (32 << 10));
    float*  w1s   = (float*) (sm + (48 << 10));
    float*  w2s   = (float*) (sm + (64 << 10));
    float4* rec   = (float4*)(sm + (80 << 10));            // 64 KB {C, ec1, ec2, s_col}

    // 1. XW + scores (+ XWT bf16)
    xw_kernel<<<NN / XROWS, NF, 0, stream>>>(X, W, a, XWT, s_col, s_row);
    // 2. order statistics for the exact rank-1 decomposition of den
    prep_kernel<<<256, 256, 0, stream>>>(s_row, s_col, ks, w1s, w2s, rec);
    // 3. exact num + att per row via dual scan (also emits bf16 A copy)
    row_kernel<<<NN, 512, 0, stream>>>(A, s_row, ks, w1s, w2s, rec, Ab, att);
    // 4. M1 = att @ XW (split-K partials)
    gemm_splitk_kernel<<<dim3(1, 32, NSPLIT), 256, 0, stream>>>(att, XWT, P);
    // 5. reduce -> M1T bf16 (col-major == B^T operand)
    reduce_t_kernel<<<(NN * NF / 4) / 256, 256, 0, stream>>>(P, M1T);
    // 6. H = A @ M1 (split-K partials)
    gemm_splitk_kernel<<<dim3(1, 32, NSPLIT), 256, 0, stream>>>(Ab, M1T, P);
    // 7. reduce -> output
    reduce_out_kernel<<<NN / 16, 256, 0, stream>>>(P, H);
}